// Round 8
// baseline (243.265 us; speedup 1.0000x reference)
//
#include <hip/hip_runtime.h>

#define DDIM  64
#define HCENT 256
#define GRID  512
#define CPB   2    // 512 rows per s-iter per block: 512*2*512 = 524288

typedef short bf16x8 __attribute__((ext_vector_type(8)));
typedef float f32x4  __attribute__((ext_vector_type(4)));

#define LOG2E 1.4426950408889634f
#define K2L   2.8853900817779268f   // 2*log2(e)
#define BIASF 80.0f

__device__ __forceinline__ float fast_exp2(float x) {
#if __has_builtin(__builtin_amdgcn_exp2f)
  return __builtin_amdgcn_exp2f(x);
#else
  return exp2f(x);
#endif
}

// Design point (round-8): the toolchain pins large blocks to a 64-VGPR arch
// budget (rounds 6-7: attribute-immune, 56 MB scratch with the reg pipeline).
// So: fit 64 VGPRs (no prefetch pipeline, unroll-1 ct loop) and take 8
// waves/EU instead: block=1024, LDS 66KB -> 2 blocks/CU = 32 waves/CU (max).
// Latency is then hidden by TLP, not per-wave pipelining.
__global__ __launch_bounds__(1024, 8)
void rbf_main(const float* __restrict__ X,
              const float* __restrict__ bptr,
              const float* __restrict__ centers,
              const float* __restrict__ w,
              float* __restrict__ out) {
  // Centers as split-bf16 MFMA B-fragments, fragment-ordered for conflict-free
  // ds_read_b128: index = (ct*2+kc)*64 + lane, 16B per lane. 32KB+32KB+2KB.
  __shared__ int4 BH[16 * 2 * 64];
  __shared__ int4 BL[16 * 2 * 64];
  __shared__ float2 CWs[HCENT];   // (mc, w) per center, computed in-block

  const int tid  = threadIdx.x;
  const int wave = tid >> 6;      // 0..15
  const int lane = tid & 63;
  const int q    = lane >> 4;     // k-group / row-quad
  const int c    = lane & 15;     // col within tile (and A-row at load)

  // ---- stage centers + per-center constants (once per block) ----
  // 16 waves <-> 16 col-tiles: wave handles ct = wave, both kc halves.
  float c2s = 0.f;
#pragma unroll
  for (int kc = 0; kc < 2; ++kc) {
    int ct = wave;
    const float* src = centers + (ct * 16 + c) * DDIM + kc * 32 + q * 8;
    f32x4 f0 = reinterpret_cast<const f32x4*>(src)[0];
    f32x4 f1 = reinterpret_cast<const f32x4*>(src)[1];
    float xs[8] = {f0.x, f0.y, f0.z, f0.w, f1.x, f1.y, f1.z, f1.w};
    int hp[4], lp[4];
#pragma unroll
    for (int p = 0; p < 4; ++p) {
      float x0 = xs[2 * p], x1 = xs[2 * p + 1];
      c2s = fmaf(x0, x0, c2s);
      c2s = fmaf(x1, x1, c2s);
      unsigned u0 = __float_as_uint(x0);
      unsigned u1 = __float_as_uint(x1);
      float l0 = x0 - __uint_as_float(u0 & 0xFFFF0000u);
      float l1 = x1 - __uint_as_float(u1 & 0xFFFF0000u);
      hp[p] = (int)__builtin_amdgcn_perm(u1, u0, 0x07060302u);
      lp[p] = (int)__builtin_amdgcn_perm(__float_as_uint(l1), __float_as_uint(l0),
                                         0x07060302u);
    }
    int idx = (ct * 2 + kc) * 64 + lane;
    BH[idx] = make_int4(hp[0], hp[1], hp[2], hp[3]);
    BL[idx] = make_int4(lp[0], lp[1], lp[2], lp[3]);
  }
  // finish c2 across the 4 q-groups; lane q==0 writes (mc, w) for this ct
  {
    float s2 = c2s;
    s2 += __shfl_xor(s2, 16, 64);
    s2 += __shfl_xor(s2, 32, 64);
    if (q == 0) {
      int h = wave * 16 + c;
      CWs[h] = make_float2(-fmaf(s2, LOG2E, BIASF), w[h]);
    }
  }

  float bval = bptr[0];

  __syncthreads();  // LDS read-only hereafter; no barrier in the sweep loop

  const bf16x8* BHv = reinterpret_cast<const bf16x8*>(BH);
  const bf16x8* BLv = reinterpret_cast<const bf16x8*>(BL);

#pragma unroll 1
  for (int s = 0; s < CPB; ++s) {
    int rowbase = (blockIdx.x * CPB + s) * 512 + wave * 32;

    // ---- issue all 8 X loads, then convert to bf16 hi/lo A-frags + x2 ----
    f32x4 r0, r1, r2, r3, r4, r5, r6, r7;
    {
      const float* rp0 = X + (rowbase + c) * DDIM + q * 8;
      const float* rp1 = X + (rowbase + 16 + c) * DDIM + q * 8;
      r0 = reinterpret_cast<const f32x4*>(rp0)[0];
      r1 = reinterpret_cast<const f32x4*>(rp0)[1];
      r2 = reinterpret_cast<const f32x4*>(rp0 + 32)[0];
      r3 = reinterpret_cast<const f32x4*>(rp0 + 32)[1];
      r4 = reinterpret_cast<const f32x4*>(rp1)[0];
      r5 = reinterpret_cast<const f32x4*>(rp1)[1];
      r6 = reinterpret_cast<const f32x4*>(rp1 + 32)[0];
      r7 = reinterpret_cast<const f32x4*>(rp1 + 32)[1];
    }

    bf16x8 ah[2][2], al[2][2];
    float x2p[2];
#pragma unroll
    for (int rt = 0; rt < 2; ++rt) {
      float part = 0.f;
#pragma unroll
      for (int kc = 0; kc < 2; ++kc) {
        f32x4 f0 = (rt == 0) ? (kc == 0 ? r0 : r2) : (kc == 0 ? r4 : r6);
        f32x4 f1 = (rt == 0) ? (kc == 0 ? r1 : r3) : (kc == 0 ? r5 : r7);
        float xs[8] = {f0.x, f0.y, f0.z, f0.w, f1.x, f1.y, f1.z, f1.w};
        union { int i[4]; bf16x8 v; } uh, ul;
#pragma unroll
        for (int p = 0; p < 4; ++p) {
          float x0 = xs[2 * p], x1 = xs[2 * p + 1];
          part = fmaf(x0, x0, part);
          part = fmaf(x1, x1, part);
          unsigned u0 = __float_as_uint(x0);
          unsigned u1 = __float_as_uint(x1);
          float l0 = x0 - __uint_as_float(u0 & 0xFFFF0000u);
          float l1 = x1 - __uint_as_float(u1 & 0xFFFF0000u);
          uh.i[p] = (int)__builtin_amdgcn_perm(u1, u0, 0x07060302u);
          ul.i[p] = (int)__builtin_amdgcn_perm(__float_as_uint(l1),
                                               __float_as_uint(l0), 0x07060302u);
        }
        ah[rt][kc] = uh.v;
        al[rt][kc] = ul.v;
      }
      x2p[rt] = part;   // k-partial; cross-k shfl deferred to epilogue
    }

    // ---- sweep 16 col-tiles (unroll 1: keeps live regs ~52 < 64) ----
    float psum[2][4] = {{0.f, 0.f, 0.f, 0.f}, {0.f, 0.f, 0.f, 0.f}};
#pragma unroll 1
    for (int ct = 0; ct < 16; ++ct) {
      int idx = ct * 128 + lane;
      bf16x8 bh0 = BHv[idx], bh1 = BHv[idx + 64];
      bf16x8 bl0 = BLv[idx], bl1 = BLv[idx + 64];
      float2 mw = CWs[ct * 16 + c];   // (mc, w) via ds_read_b64, broadcast over q
#pragma unroll
      for (int rt = 0; rt < 2; ++rt) {
        f32x4 acc = {0.f, 0.f, 0.f, 0.f};
        acc = __builtin_amdgcn_mfma_f32_16x16x32_bf16(ah[rt][0], bh0, acc, 0, 0, 0);
        acc = __builtin_amdgcn_mfma_f32_16x16x32_bf16(ah[rt][1], bh1, acc, 0, 0, 0);
        acc = __builtin_amdgcn_mfma_f32_16x16x32_bf16(al[rt][0], bh0, acc, 0, 0, 0);
        acc = __builtin_amdgcn_mfma_f32_16x16x32_bf16(al[rt][1], bh1, acc, 0, 0, 0);
        acc = __builtin_amdgcn_mfma_f32_16x16x32_bf16(ah[rt][0], bl0, acc, 0, 0, 0);
        acc = __builtin_amdgcn_mfma_f32_16x16x32_bf16(ah[rt][1], bl1, acc, 0, 0, 0);
        // contribution = exp2(2L*a - (L*c2+B)) * w; row factor applied later
#pragma unroll
        for (int r = 0; r < 4; ++r) {
          float e = fast_exp2(fmaf(acc[r], K2L, mw.x));
          psum[rt][r] = fmaf(e, mw.y, psum[rt][r]);
        }
      }
    }

    // ---- reduce over the 16 col-lanes, apply row factor, store ----
#pragma unroll
    for (int rt = 0; rt < 2; ++rt) {
      float part = x2p[rt];
      part += __shfl_xor(part, 16, 64);
      part += __shfl_xor(part, 32, 64);
#pragma unroll
      for (int r = 0; r < 4; ++r) {
        float v = psum[rt][r];
        v += __shfl_xor(v, 1, 64);
        v += __shfl_xor(v, 2, 64);
        v += __shfl_xor(v, 4, 64);
        v += __shfl_xor(v, 8, 64);
        // x2 of row q*4+r lives in lanes with c == q*4+r (replicated over q)
        float x2row = __shfl(part, q * 4 + r, 64);
        float rowf = fast_exp2(fmaf(-LOG2E, x2row, BIASF));
        psum[rt][r] = fmaf(v, rowf, bval);
      }
      if (c == 0) {
        f32x4 o = {psum[rt][0], psum[rt][1], psum[rt][2], psum[rt][3]};
        *reinterpret_cast<f32x4*>(out + rowbase + rt * 16 + q * 4) = o;
      }
    }
  }
}

extern "C" void kernel_launch(void* const* d_in, const int* in_sizes, int n_in,
                              void* d_out, int out_size, void* d_ws, size_t ws_size,
                              hipStream_t stream) {
  const float* X       = (const float*)d_in[0];
  const float* centers = (const float*)d_in[1];
  const float* w       = (const float*)d_in[2];
  const float* b       = (const float*)d_in[3];
  float* out = (float*)d_out;

  rbf_main<<<GRID, 1024, 0, stream>>>(X, b, centers, w, out);
}